// Round 1
// baseline (1508.950 us; speedup 1.0000x reference)
//
#include <hip/hip_runtime.h>

// Problem constants (from reference setup_inputs)
constexpr int N = 50000;   // nodes
constexpr int E = 800000;  // edges
constexpr int F = 128;     // feature dim
constexpr int U = 256;     // output units

// ---------------------------------------------------------------------------
// 1) in-degree accumulation: deg[row[e]] += val[e]
// ---------------------------------------------------------------------------
__global__ __launch_bounds__(256) void deg_kernel(const int* __restrict__ erow,
                                                  const float* __restrict__ eval,
                                                  float* __restrict__ deg) {
    int e = blockIdx.x * 256 + threadIdx.x;
    if (e < E) atomicAdd(&deg[erow[e]], eval[e]);
}

// ---------------------------------------------------------------------------
// 2) inv[i] = rsqrt(deg[i] + 1)
// ---------------------------------------------------------------------------
__global__ __launch_bounds__(256) void inv_kernel(const float* __restrict__ deg,
                                                  float* __restrict__ inv) {
    int i = blockIdx.x * 256 + threadIdx.x;
    if (i < N) inv[i] = rsqrtf(deg[i] + 1.0f);
}

// ---------------------------------------------------------------------------
// 3) normalized = inv * feat ; pooled (init) = inv * normalized  (self loop)
//    one thread per float4 chunk: tid over N*32
// ---------------------------------------------------------------------------
__global__ __launch_bounds__(256) void norm_init_kernel(const float* __restrict__ feat,
                                                        const float* __restrict__ inv,
                                                        float* __restrict__ nrm,
                                                        float* __restrict__ pooled) {
    int tid = blockIdx.x * 256 + threadIdx.x;  // exactly N*32 threads
    int node = tid >> 5;
    int q    = tid & 31;
    float iv = inv[node];
    float4 f = ((const float4*)feat)[node * 32 + q];
    float4 nv = make_float4(iv * f.x, iv * f.y, iv * f.z, iv * f.w);
    ((float4*)nrm)[node * 32 + q] = nv;
    ((float4*)pooled)[node * 32 + q] =
        make_float4(iv * nv.x, iv * nv.y, iv * nv.z, iv * nv.w);
}

// ---------------------------------------------------------------------------
// 4) edge scatter: pooled[row] += val * normalized[col]
//    32 threads per edge, each handles one float4 chunk (4 scalar atomics)
// ---------------------------------------------------------------------------
__global__ __launch_bounds__(256) void scatter_kernel(const int* __restrict__ erow,
                                                      const int* __restrict__ ecol,
                                                      const float* __restrict__ eval,
                                                      const float* __restrict__ nrm,
                                                      float* __restrict__ pooled) {
    int tid = blockIdx.x * 256 + threadIdx.x;  // exactly E*32 threads
    int e = tid >> 5;
    int q = tid & 31;
    int r = erow[e];
    int c = ecol[e];
    float v = eval[e];
    float4 nv = ((const float4*)nrm)[c * 32 + q];
    float* dst = pooled + (size_t)r * F + q * 4;
    atomicAdd(dst + 0, v * nv.x);
    atomicAdd(dst + 1, v * nv.y);
    atomicAdd(dst + 2, v * nv.z);
    atomicAdd(dst + 3, v * nv.w);
}

// ---------------------------------------------------------------------------
// 5) out = relu(pooled @ W)   [N,128] @ [128,256] -> [N,256], fp32 vector ALU
//    block: 256 threads -> 64x64 output tile, K staged in two 64-chunks.
//    As padded to 66 floats/row: inner-loop a-reads land on distinct banks
//    (66 % 32 == 2 spreads ty), Ws b128 reads are 2-way (free per m136).
// ---------------------------------------------------------------------------
__global__ __launch_bounds__(256) void gemm_relu_kernel(const float* __restrict__ A,
                                                        const float* __restrict__ W,
                                                        float* __restrict__ out) {
    __shared__ float As[64][66];
    __shared__ float Ws[64][64];
    const int m0 = blockIdx.x * 64;
    const int c0 = blockIdx.y * 64;
    const int tid = threadIdx.x;
    const int tx = tid & 15;   // 16 cols of float4
    const int ty = tid >> 4;   // 16 row groups

    float acc[4][4] = {};

    for (int kb = 0; kb < F; kb += 64) {
        // stage A tile (64 rows x 64 k), coalesced float4 global reads
        #pragma unroll
        for (int it = 0; it < 4; ++it) {
            int idx = it * 256 + tid;   // 0..1023
            int m = idx >> 4;           // 0..63
            int q = idx & 15;           // float4 index within 64-wide K chunk
            int row = m0 + m;
            float4 a = (row < N) ? ((const float4*)A)[(size_t)row * (F / 4) + (kb >> 2) + q]
                                 : make_float4(0.f, 0.f, 0.f, 0.f);
            As[m][q * 4 + 0] = a.x;
            As[m][q * 4 + 1] = a.y;
            As[m][q * 4 + 2] = a.z;
            As[m][q * 4 + 3] = a.w;
        }
        // stage W tile (64 k x 64 cols)
        #pragma unroll
        for (int it = 0; it < 4; ++it) {
            int idx = it * 256 + tid;
            int k = idx >> 4;   // 0..63
            int q = idx & 15;
            float4 w = ((const float4*)W)[(size_t)(kb + k) * (U / 4) + (c0 >> 2) + q];
            *(float4*)&Ws[k][q * 4] = w;
        }
        __syncthreads();

        #pragma unroll 8
        for (int k = 0; k < 64; ++k) {
            float a0 = As[ty * 4 + 0][k];
            float a1 = As[ty * 4 + 1][k];
            float a2 = As[ty * 4 + 2][k];
            float a3 = As[ty * 4 + 3][k];
            float4 w = *(float4*)&Ws[k][tx * 4];
            acc[0][0] += a0 * w.x; acc[0][1] += a0 * w.y; acc[0][2] += a0 * w.z; acc[0][3] += a0 * w.w;
            acc[1][0] += a1 * w.x; acc[1][1] += a1 * w.y; acc[1][2] += a1 * w.z; acc[1][3] += a1 * w.w;
            acc[2][0] += a2 * w.x; acc[2][1] += a2 * w.y; acc[2][2] += a2 * w.z; acc[2][3] += a2 * w.w;
            acc[3][0] += a3 * w.x; acc[3][1] += a3 * w.y; acc[3][2] += a3 * w.z; acc[3][3] += a3 * w.w;
        }
        __syncthreads();
    }

    #pragma unroll
    for (int i = 0; i < 4; ++i) {
        int row = m0 + ty * 4 + i;
        if (row < N) {
            float4 o = make_float4(fmaxf(acc[i][0], 0.f), fmaxf(acc[i][1], 0.f),
                                   fmaxf(acc[i][2], 0.f), fmaxf(acc[i][3], 0.f));
            ((float4*)out)[(size_t)row * (U / 4) + (c0 >> 2) + tx] = o;
        }
    }
}

// ---------------------------------------------------------------------------
extern "C" void kernel_launch(void* const* d_in, const int* in_sizes, int n_in,
                              void* d_out, int out_size, void* d_ws, size_t ws_size,
                              hipStream_t stream) {
    (void)in_sizes; (void)n_in; (void)out_size; (void)ws_size;

    const float* feat = (const float*)d_in[0];  // [N,128]
    const int*   erow = (const int*)d_in[1];    // [E]
    const int*   ecol = (const int*)d_in[2];    // [E]
    const float* eval = (const float*)d_in[3];  // [E]
    const float* W    = (const float*)d_in[4];  // [128,256]
    float* out = (float*)d_out;                 // [N,256]

    // workspace layout (floats): deg[N] | inv[N] | normalized[N*128] | pooled[N*128]
    float* ws     = (float*)d_ws;
    float* deg    = ws;                      // N
    float* inv    = ws + N;                  // N
    float* nrm    = ws + 2 * (size_t)N;      // N*F
    float* pooled = nrm + (size_t)N * F;     // N*F   (total ~51.6 MB)

    hipMemsetAsync(deg, 0, (size_t)N * sizeof(float), stream);

    deg_kernel<<<(E + 255) / 256, 256, 0, stream>>>(erow, eval, deg);
    inv_kernel<<<(N + 255) / 256, 256, 0, stream>>>(deg, inv);
    norm_init_kernel<<<(N * 32) / 256, 256, 0, stream>>>(feat, inv, nrm, pooled);
    scatter_kernel<<<(E * 32) / 256, 256, 0, stream>>>(erow, ecol, eval, nrm, pooled);

    dim3 ggrid((N + 63) / 64, U / 64);
    gemm_relu_kernel<<<ggrid, 256, 0, stream>>>(pooled, W, out);
}

// Round 2
// 478.046 us; speedup vs baseline: 3.1565x; 3.1565x over previous
//
#include <hip/hip_runtime.h>

// Problem constants (from reference setup_inputs)
constexpr int N = 50000;   // nodes
constexpr int E = 800000;  // edges
constexpr int F = 128;     // feature dim
constexpr int U = 256;     // output units

__device__ inline unsigned short f32_to_bf16(float x) {
    unsigned int u = __float_as_uint(x);
    unsigned int r = (u + 0x7fffu + ((u >> 16) & 1u)) >> 16;  // RNE
    return (unsigned short)r;
}

// ---------------------------------------------------------------------------
// 1) histogram: cnt[row]++ and deg[row] += val   (1.6M light atomics)
// ---------------------------------------------------------------------------
__global__ __launch_bounds__(256) void hist_kernel(const int* __restrict__ erow,
                                                   const float* __restrict__ eval,
                                                   float* __restrict__ deg,
                                                   int* __restrict__ cnt) {
    int e = blockIdx.x * 256 + threadIdx.x;
    if (e < E) {
        int r = erow[e];
        atomicAdd(&deg[r], eval[e]);
        atomicAdd(&cnt[r], 1);
    }
}

// ---------------------------------------------------------------------------
// 2) exclusive scan of cnt -> row_ptr[N+1], cursor (single block of 1024)
// ---------------------------------------------------------------------------
__global__ __launch_bounds__(1024) void scan_kernel(const int* __restrict__ cnt,
                                                    int* __restrict__ row_ptr,
                                                    int* __restrict__ cursor) {
    __shared__ int sums[1024];
    const int T = 1024;
    const int t = threadIdx.x;
    const int chunk = (N + T - 1) / T;  // 49
    const int base = t * chunk;
    int s = 0;
    for (int i = 0; i < chunk; ++i) {
        int idx = base + i;
        if (idx < N) s += cnt[idx];
    }
    sums[t] = s;
    __syncthreads();
    // Hillis-Steele inclusive scan
    for (int off = 1; off < T; off <<= 1) {
        int u = (t >= off) ? sums[t - off] : 0;
        __syncthreads();
        sums[t] += u;
        __syncthreads();
    }
    int run = sums[t] - s;  // exclusive prefix for this thread's chunk
    for (int i = 0; i < chunk; ++i) {
        int idx = base + i;
        if (idx < N) {
            row_ptr[idx] = run;
            cursor[idx]  = run;
            run += cnt[idx];
        }
    }
    if (t == T - 1) row_ptr[N] = run;  // == E
}

// ---------------------------------------------------------------------------
// 3) permute edges into CSR order (counting sort placement)
// ---------------------------------------------------------------------------
__global__ __launch_bounds__(256) void permute_kernel(const int* __restrict__ erow,
                                                      const int* __restrict__ ecol,
                                                      const float* __restrict__ eval,
                                                      int* __restrict__ cursor,
                                                      int* __restrict__ csr_col,
                                                      float* __restrict__ csr_val) {
    int e = blockIdx.x * 256 + threadIdx.x;
    if (e < E) {
        int r = erow[e];
        int p = atomicAdd(&cursor[r], 1);
        csr_col[p] = ecol[e];
        csr_val[p] = eval[e];
    }
}

// ---------------------------------------------------------------------------
// 4) normalized = rsqrt(deg+1) * feat, stored as bf16 (halves gather traffic)
//    32 threads per node, each handles 4 feats (float4 read, ushort4 write)
// ---------------------------------------------------------------------------
__global__ __launch_bounds__(256) void norm_kernel(const float* __restrict__ feat,
                                                   const float* __restrict__ deg,
                                                   unsigned short* __restrict__ nrm) {
    int tid = blockIdx.x * 256 + threadIdx.x;  // exactly N*32 threads
    int node = tid >> 5;
    int q    = tid & 31;
    float iv = rsqrtf(deg[node] + 1.0f);
    float4 f = ((const float4*)feat)[node * 32 + q];
    ushort4 o;
    o.x = f32_to_bf16(iv * f.x);
    o.y = f32_to_bf16(iv * f.y);
    o.z = f32_to_bf16(iv * f.z);
    o.w = f32_to_bf16(iv * f.w);
    ((ushort4*)nrm)[node * 32 + q] = o;
}

// ---------------------------------------------------------------------------
// 5) gather: pooled[n] = inv^2*feat[n] + sum_{e in row n} val[e]*nrm[col[e]]
//    one wave (64 lanes) per node, each lane owns 2 feature slots
// ---------------------------------------------------------------------------
__global__ __launch_bounds__(256) void gather_kernel(const int* __restrict__ row_ptr,
                                                     const int* __restrict__ csr_col,
                                                     const float* __restrict__ csr_val,
                                                     const unsigned short* __restrict__ nrm,
                                                     const float* __restrict__ deg,
                                                     const float* __restrict__ feat,
                                                     float* __restrict__ pooled) {
    int gtid = blockIdx.x * 256 + threadIdx.x;
    int n    = gtid >> 6;       // node (one wave each)
    int lane = threadIdx.x & 63;
    if (n >= N) return;

    float iv  = rsqrtf(deg[n] + 1.0f);
    float iv2 = iv * iv;
    float2 f = ((const float2*)feat)[n * 64 + lane];
    float acc0 = iv2 * f.x;
    float acc1 = iv2 * f.y;

    int e0 = row_ptr[n], e1 = row_ptr[n + 1];
    for (int e = e0; e < e1; ++e) {
        int   c = csr_col[e];
        float v = csr_val[e];
        unsigned int u = *(const unsigned int*)&nrm[(size_t)c * F + lane * 2];
        float n0 = __uint_as_float(u << 16);
        float n1 = __uint_as_float(u & 0xffff0000u);
        acc0 += v * n0;
        acc1 += v * n1;
    }
    ((float2*)pooled)[n * 64 + lane] = make_float2(acc0, acc1);
}

// ---------------------------------------------------------------------------
// 6) out = relu(pooled @ W)  [N,128]@[128,256] fp32 vector ALU
//    128x128 tile / 256 threads / 8x8 per thread; As stored transposed [k][m]
//    so all fragment reads are ds_read_b128 with <=2-way bank aliasing.
// ---------------------------------------------------------------------------
__global__ __launch_bounds__(256, 4) void gemm_relu_kernel(const float* __restrict__ A,
                                                           const float* __restrict__ Wm,
                                                           float* __restrict__ out) {
    constexpr int BK = 32;
    __shared__ float As[BK][132];  // As[k][m]
    __shared__ float Ws[BK][132];  // Ws[k][c]
    const int m0 = blockIdx.x * 128;
    const int c0 = blockIdx.y * 128;
    const int tid = threadIdx.x;
    const int tx = tid & 15;   // 16 col groups
    const int ty = tid >> 4;   // 16 row groups

    float acc[8][8] = {};  // rows: mh*4+mi (m = mh*64+ty*4+mi); cols: ch*4+cj

    const int sm   = tid >> 1;       // staging: row within tile (0..127)
    const int half = tid & 1;        // staging: which 16-k half

    for (int kb = 0; kb < F; kb += BK) {
        // --- stage A (transposed into As[k][m]) ---
        {
            int row = m0 + sm;
            float4 a[4];
            if (row < N) {
                const float4* src = (const float4*)(A + (size_t)row * F + kb + half * 16);
                a[0] = src[0]; a[1] = src[1]; a[2] = src[2]; a[3] = src[3];
            } else {
                a[0] = a[1] = a[2] = a[3] = make_float4(0.f, 0.f, 0.f, 0.f);
            }
            #pragma unroll
            for (int j = 0; j < 4; ++j) {
                const float* af = (const float*)&a[j];
                #pragma unroll
                for (int t = 0; t < 4; ++t)
                    As[half * 16 + j * 4 + t][sm] = af[t];
            }
        }
        // --- stage W (Ws[k][c]) ---
        {
            int cq = tid & 31;       // float4 col index (c = cq*4)
            int kb8 = tid >> 5;      // 0..7
            #pragma unroll
            for (int it = 0; it < 4; ++it) {
                int k = kb8 + it * 8;
                float4 w = ((const float4*)Wm)[(size_t)(kb + k) * (U / 4) + (c0 >> 2) + cq];
                *(float4*)&Ws[k][cq * 4] = w;
            }
        }
        __syncthreads();

        #pragma unroll 8
        for (int k = 0; k < BK; ++k) {
            float4 a0 = *(const float4*)&As[k][ty * 4];
            float4 a1 = *(const float4*)&As[k][64 + ty * 4];
            float4 w0 = *(const float4*)&Ws[k][tx * 4];
            float4 w1 = *(const float4*)&Ws[k][64 + tx * 4];
            const float am[8] = {a0.x, a0.y, a0.z, a0.w, a1.x, a1.y, a1.z, a1.w};
            const float wc[8] = {w0.x, w0.y, w0.z, w0.w, w1.x, w1.y, w1.z, w1.w};
            #pragma unroll
            for (int i = 0; i < 8; ++i)
                #pragma unroll
                for (int j = 0; j < 8; ++j)
                    acc[i][j] += am[i] * wc[j];
        }
        __syncthreads();
    }

    #pragma unroll
    for (int mh = 0; mh < 2; ++mh) {
        #pragma unroll
        for (int i = 0; i < 4; ++i) {
            int row = m0 + mh * 64 + ty * 4 + i;
            if (row < N) {
                #pragma unroll
                for (int ch = 0; ch < 2; ++ch) {
                    float4 o = make_float4(fmaxf(acc[mh * 4 + i][ch * 4 + 0], 0.f),
                                           fmaxf(acc[mh * 4 + i][ch * 4 + 1], 0.f),
                                           fmaxf(acc[mh * 4 + i][ch * 4 + 2], 0.f),
                                           fmaxf(acc[mh * 4 + i][ch * 4 + 3], 0.f));
                    ((float4*)out)[(size_t)row * (U / 4) + (c0 >> 2) + ch * 16 + tx] = o;
                }
            }
        }
    }
}

// ---------------------------------------------------------------------------
extern "C" void kernel_launch(void* const* d_in, const int* in_sizes, int n_in,
                              void* d_out, int out_size, void* d_ws, size_t ws_size,
                              hipStream_t stream) {
    (void)in_sizes; (void)n_in; (void)out_size; (void)ws_size;

    const float* feat = (const float*)d_in[0];  // [N,128]
    const int*   erow = (const int*)d_in[1];    // [E]
    const int*   ecol = (const int*)d_in[2];    // [E]
    const float* eval = (const float*)d_in[3];  // [E]
    const float* W    = (const float*)d_in[4];  // [128,256]
    float* out = (float*)d_out;                 // [N,256]

    // workspace layout (byte offsets, 64B-aligned blocks)
    char* ws = (char*)d_ws;
    float*          deg     = (float*)(ws + 0);                   // N      (200000 B)
    int*            cnt     = (int*)  (ws + 200000);              // N      (200000 B)
    int*            row_ptr = (int*)  (ws + 400000);              // N+1    (200004 B)
    int*            cursor  = (int*)  (ws + 600064);              // N      (200000 B)
    int*            csr_col = (int*)  (ws + 800064);              // E      (3.2 MB)
    float*          csr_val = (float*)(ws + 4000064);             // E      (3.2 MB)
    unsigned short* nrm     = (unsigned short*)(ws + 7200064);    // N*F bf16 (12.8 MB)
    float*          pooled  = (float*)(ws + 20000064);            // N*F f32  (25.6 MB)
    // total ~45.6 MB

    hipMemsetAsync(ws, 0, 400000, stream);  // deg + cnt

    hist_kernel<<<(E + 255) / 256, 256, 0, stream>>>(erow, eval, deg, cnt);
    scan_kernel<<<1, 1024, 0, stream>>>(cnt, row_ptr, cursor);
    permute_kernel<<<(E + 255) / 256, 256, 0, stream>>>(erow, ecol, eval, cursor, csr_col, csr_val);
    norm_kernel<<<(N * 32) / 256, 256, 0, stream>>>(feat, deg, nrm);
    gather_kernel<<<(N * 64) / 256, 256, 0, stream>>>(row_ptr, csr_col, csr_val, nrm, deg, feat, pooled);

    dim3 ggrid((N + 127) / 128, U / 128);
    gemm_relu_kernel<<<ggrid, 256, 0, stream>>>(pooled, W, out);
}

// Round 4
// 302.663 us; speedup vs baseline: 4.9856x; 1.5795x over previous
//
#include <hip/hip_runtime.h>

// Problem constants (from reference setup_inputs)
constexpr int N = 50000;   // nodes
constexpr int E = 800000;  // edges
constexpr int F = 128;     // feature dim
constexpr int U = 256;     // output units

typedef __attribute__((ext_vector_type(8))) short short8;
typedef __attribute__((ext_vector_type(4))) float float4v;

__device__ inline unsigned short f32_to_bf16(float x) {
    unsigned int u = __float_as_uint(x);
    unsigned int r = (u + 0x7fffu + ((u >> 16) & 1u)) >> 16;  // RNE
    return (unsigned short)r;
}

// ---------------------------------------------------------------------------
// 1) histogram: cnt[row]++ and deg[row] += val
// ---------------------------------------------------------------------------
__global__ __launch_bounds__(256) void hist_kernel(const int* __restrict__ erow,
                                                   const float* __restrict__ eval,
                                                   float* __restrict__ deg,
                                                   int* __restrict__ cnt) {
    int e = blockIdx.x * 256 + threadIdx.x;
    if (e < E) {
        int r = erow[e];
        atomicAdd(&deg[r], eval[e]);
        atomicAdd(&cnt[r], 1);
    }
}

// ---------------------------------------------------------------------------
// 2a) per-block sums of cnt (196 blocks x 256)
// ---------------------------------------------------------------------------
__global__ __launch_bounds__(256) void blksum_kernel(const int* __restrict__ cnt,
                                                     int* __restrict__ blk_sum) {
    int i = blockIdx.x * 256 + threadIdx.x;
    int v = (i < N) ? cnt[i] : 0;
    #pragma unroll
    for (int off = 32; off > 0; off >>= 1) v += __shfl_down(v, off, 64);
    __shared__ int s[4];
    if ((threadIdx.x & 63) == 0) s[threadIdx.x >> 6] = v;
    __syncthreads();
    if (threadIdx.x == 0) blk_sum[blockIdx.x] = s[0] + s[1] + s[2] + s[3];
}

// ---------------------------------------------------------------------------
// 2b) exclusive scan of the 196 block sums (1 block x 256)
// ---------------------------------------------------------------------------
__global__ __launch_bounds__(256) void scansum_kernel(const int* __restrict__ blk_sum,
                                                      int* __restrict__ blk_off,
                                                      int* __restrict__ row_ptr) {
    __shared__ int sh[256];
    int t = threadIdx.x;
    int v = (t < 196) ? blk_sum[t] : 0;
    sh[t] = v;
    __syncthreads();
    for (int off = 1; off < 256; off <<= 1) {
        int u = (t >= off) ? sh[t - off] : 0;
        __syncthreads();
        sh[t] += u;
        __syncthreads();
    }
    blk_off[t] = sh[t] - v;  // exclusive
    if (t == 0) row_ptr[N] = E;
}

// ---------------------------------------------------------------------------
// 2c) per-block scan + global offset -> row_ptr, cursor (196 blocks x 256)
// ---------------------------------------------------------------------------
__global__ __launch_bounds__(256) void blkscan_kernel(const int* __restrict__ cnt,
                                                      const int* __restrict__ blk_off,
                                                      int* __restrict__ row_ptr,
                                                      int* __restrict__ cursor) {
    __shared__ int sh[256];
    int t = threadIdx.x;
    int i = blockIdx.x * 256 + t;
    int v = (i < N) ? cnt[i] : 0;
    sh[t] = v;
    __syncthreads();
    for (int off = 1; off < 256; off <<= 1) {
        int u = (t >= off) ? sh[t - off] : 0;
        __syncthreads();
        sh[t] += u;
        __syncthreads();
    }
    if (i < N) {
        int ex = blk_off[blockIdx.x] + sh[t] - v;
        row_ptr[i] = ex;
        cursor[i]  = ex;
    }
}

// ---------------------------------------------------------------------------
// 3) permute edges into CSR order, interleaved {col, val_bits}
// ---------------------------------------------------------------------------
__global__ __launch_bounds__(256) void permute_kernel(const int* __restrict__ erow,
                                                      const int* __restrict__ ecol,
                                                      const float* __restrict__ eval,
                                                      int* __restrict__ cursor,
                                                      int2* __restrict__ csr) {
    int e = blockIdx.x * 256 + threadIdx.x;
    if (e < E) {
        int r = erow[e];
        int p = atomicAdd(&cursor[r], 1);
        csr[p] = make_int2(ecol[e], __float_as_int(eval[e]));
    }
}

// ---------------------------------------------------------------------------
// 4) normalized = rsqrt(deg+1) * feat, stored bf16
// ---------------------------------------------------------------------------
__global__ __launch_bounds__(256) void norm_kernel(const float* __restrict__ feat,
                                                   const float* __restrict__ deg,
                                                   unsigned short* __restrict__ nrm) {
    int tid = blockIdx.x * 256 + threadIdx.x;  // exactly N*32 threads
    int node = tid >> 5;
    int q    = tid & 31;
    float iv = rsqrtf(deg[node] + 1.0f);
    float4 f = ((const float4*)feat)[node * 32 + q];
    ushort4 o;
    o.x = f32_to_bf16(iv * f.x);
    o.y = f32_to_bf16(iv * f.y);
    o.z = f32_to_bf16(iv * f.z);
    o.w = f32_to_bf16(iv * f.w);
    ((ushort4*)nrm)[node * 32 + q] = o;
}

// ---------------------------------------------------------------------------
// 5) gather: pooled[n] = inv^2*feat[n] + sum_e val*nrm[col]  -> bf16 output
//    one wave per node, lane owns 2 feature slots; 2-edge unroll for ILP
// ---------------------------------------------------------------------------
__global__ __launch_bounds__(256) void gather_kernel(const int* __restrict__ row_ptr,
                                                     const int2* __restrict__ csr,
                                                     const unsigned short* __restrict__ nrm,
                                                     const float* __restrict__ deg,
                                                     const float* __restrict__ feat,
                                                     unsigned int* __restrict__ pooledb) {
    int gtid = blockIdx.x * 256 + threadIdx.x;
    int n    = gtid >> 6;
    int lane = threadIdx.x & 63;
    if (n >= N) return;

    float iv  = rsqrtf(deg[n] + 1.0f);
    float iv2 = iv * iv;
    float2 f = ((const float2*)feat)[n * 64 + lane];
    float acc0 = iv2 * f.x;
    float acc1 = iv2 * f.y;

    int e = row_ptr[n], e1 = row_ptr[n + 1];
    for (; e + 1 < e1; e += 2) {
        int2 p0 = csr[e];
        int2 p1 = csr[e + 1];
        unsigned int u0 = *(const unsigned int*)&nrm[(size_t)p0.x * F + lane * 2];
        unsigned int u1 = *(const unsigned int*)&nrm[(size_t)p1.x * F + lane * 2];
        float v0 = __int_as_float(p0.y), v1 = __int_as_float(p1.y);
        acc0 += v0 * __uint_as_float(u0 << 16);
        acc1 += v0 * __uint_as_float(u0 & 0xffff0000u);
        acc0 += v1 * __uint_as_float(u1 << 16);
        acc1 += v1 * __uint_as_float(u1 & 0xffff0000u);
    }
    if (e < e1) {
        int2 p0 = csr[e];
        unsigned int u0 = *(const unsigned int*)&nrm[(size_t)p0.x * F + lane * 2];
        float v0 = __int_as_float(p0.y);
        acc0 += v0 * __uint_as_float(u0 << 16);
        acc1 += v0 * __uint_as_float(u0 & 0xffff0000u);
    }
    pooledb[n * 64 + lane] =
        (unsigned int)f32_to_bf16(acc0) | ((unsigned int)f32_to_bf16(acc1) << 16);
}

// ---------------------------------------------------------------------------
// 6) W [128,256] f32 -> Wt [256,128] bf16 (transposed, for B-fragment reads)
// ---------------------------------------------------------------------------
__global__ __launch_bounds__(256) void wt_kernel(const float* __restrict__ W,
                                                 unsigned short* __restrict__ Wt) {
    int idx = blockIdx.x * 256 + threadIdx.x;  // 32768 = 128*256
    int k = idx >> 8;
    int n = idx & 255;
    Wt[n * F + k] = f32_to_bf16(W[idx]);  // coalesced read, scattered 2B write (tiny)
}

// ---------------------------------------------------------------------------
// 7) out = relu(pooled_bf16 @ W)  via MFMA 16x16x32 bf16.
//    K=128 staged once; LDS holds A and B pre-swizzled in exact fragment order
//    [ks][tile][lane][8 bf16] so every fragment read is one ds_read_b128.
//    Block tile 128(m) x 128(n), 4 waves, each wave 8 m-tiles x 2 n-tiles.
// ---------------------------------------------------------------------------
__global__ __launch_bounds__(256) void gemm_mfma_kernel(const unsigned short* __restrict__ Ab,
                                                        const unsigned short* __restrict__ Wt,
                                                        float* __restrict__ out) {
    __shared__ unsigned short As[16384];  // 32 KB, [ks(4)][mt(8)][lane(64)][8]
    __shared__ unsigned short Bs[16384];  // 32 KB, [ks(4)][nt(8)][lane(64)][8]
    const int tid = threadIdx.x;
    const int m0 = blockIdx.x * 128;
    const int n0 = blockIdx.y * 128;

    // --- stage, swizzled into fragment order ---
    {
        const int r = tid >> 1;        // 0..127 (row within tile)
        const int h = tid & 1;         // which 64-element half of K
        const int grow = m0 + r;
        const uint4* asrc = (grow < N) ? (const uint4*)(Ab + (size_t)grow * F) : nullptr;
        const uint4* bsrc = (const uint4*)(Wt + (size_t)(n0 + r) * F);
        #pragma unroll
        for (int j = 0; j < 8; ++j) {
            int o = h * 8 + j;                 // k-octet 0..15 (k = o*8)
            int ks = o >> 2, quad = o & 3;
            int slot = ((ks * 8 + (r >> 4)) * 64) + (quad << 4) + (r & 15);
            uint4 av = asrc ? asrc[o] : make_uint4(0u, 0u, 0u, 0u);
            ((uint4*)As)[slot] = av;
            ((uint4*)Bs)[slot] = bsrc[o];
        }
    }
    __syncthreads();

    const int wave = tid >> 6;
    const int lane = tid & 63;
    float4v acc[8][2];
    #pragma unroll
    for (int i = 0; i < 8; ++i) {
        acc[i][0] = (float4v){0.f, 0.f, 0.f, 0.f};
        acc[i][1] = (float4v){0.f, 0.f, 0.f, 0.f};
    }

    #pragma unroll
    for (int ks = 0; ks < 4; ++ks) {
        short8 b0 = *(const short8*)&Bs[(((ks * 8 + wave * 2 + 0) * 64) + lane) * 8];
        short8 b1 = *(const short8*)&Bs[(((ks * 8 + wave * 2 + 1) * 64) + lane) * 8];
        #pragma unroll
        for (int mt = 0; mt < 8; ++mt) {
            short8 a = *(const short8*)&As[(((ks * 8 + mt) * 64) + lane) * 8];
            acc[mt][0] = __builtin_amdgcn_mfma_f32_16x16x32_bf16(a, b0, acc[mt][0], 0, 0, 0);
            acc[mt][1] = __builtin_amdgcn_mfma_f32_16x16x32_bf16(a, b1, acc[mt][1], 0, 0, 0);
        }
    }

    // C/D layout: col = lane&15, row = (lane>>4)*4 + reg   [m89-verified]
    const int quad = lane >> 4;
    const int colt = lane & 15;
    #pragma unroll
    for (int mt = 0; mt < 8; ++mt) {
        #pragma unroll
        for (int nt = 0; nt < 2; ++nt) {
            int col = n0 + (wave * 2 + nt) * 16 + colt;
            #pragma unroll
            for (int i = 0; i < 4; ++i) {
                int row = m0 + mt * 16 + quad * 4 + i;
                if (row < N) out[(size_t)row * U + col] = fmaxf(acc[mt][nt][i], 0.f);
            }
        }
    }
}

// ---------------------------------------------------------------------------
extern "C" void kernel_launch(void* const* d_in, const int* in_sizes, int n_in,
                              void* d_out, int out_size, void* d_ws, size_t ws_size,
                              hipStream_t stream) {
    (void)in_sizes; (void)n_in; (void)out_size; (void)ws_size;

    const float* feat = (const float*)d_in[0];  // [N,128]
    const int*   erow = (const int*)d_in[1];    // [E]
    const int*   ecol = (const int*)d_in[2];    // [E]
    const float* eval = (const float*)d_in[3];  // [E]
    const float* W    = (const float*)d_in[4];  // [128,256]
    float* out = (float*)d_out;                 // [N,256]

    // workspace layout (byte offsets, 64B-aligned)
    char* ws = (char*)d_ws;
    float*          deg     = (float*)(ws + 0);          // N        (200000)
    int*            cnt     = (int*)  (ws + 200000);     // N        (200000)
    int*            row_ptr = (int*)  (ws + 400000);     // N+1
    int*            cursor  = (int*)  (ws + 600064);     // N
    int*            blk_sum = (int*)  (ws + 800064);     // 256
    int*            blk_off = (int*)  (ws + 801088);     // 256
    int2*           csr     = (int2*) (ws + 802176);     // E int2   (6.4 MB)
    unsigned short* Wt      = (unsigned short*)(ws + 7202176);   // 256*128 bf16 (64 KB)
    unsigned short* nrm     = (unsigned short*)(ws + 7267712);   // N*F bf16 (12.8 MB)
    unsigned int*   pooledb = (unsigned int*)  (ws + 20067712);  // N*F bf16 (12.8 MB)
    // total ~32.9 MB

    (void)hipMemsetAsync(ws, 0, 400000, stream);  // deg + cnt

    hist_kernel<<<(E + 255) / 256, 256, 0, stream>>>(erow, eval, deg, cnt);

    const int SBLK = (N + 255) / 256;  // 196
    blksum_kernel <<<SBLK, 256, 0, stream>>>(cnt, blk_sum);
    scansum_kernel<<<1,    256, 0, stream>>>(blk_sum, blk_off, row_ptr);
    blkscan_kernel<<<SBLK, 256, 0, stream>>>(cnt, blk_off, row_ptr, cursor);

    permute_kernel<<<(E + 255) / 256, 256, 0, stream>>>(erow, ecol, eval, cursor, csr);
    norm_kernel<<<(N * 32) / 256, 256, 0, stream>>>(feat, deg, nrm);
    wt_kernel<<<(F * U) / 256, 256, 0, stream>>>(W, Wt);
    gather_kernel<<<(N * 64) / 256, 256, 0, stream>>>(row_ptr, csr, nrm, deg, feat, pooledb);

    dim3 ggrid((N + 127) / 128, U / 128);
    gemm_mfma_kernel<<<ggrid, 256, 0, stream>>>((const unsigned short*)pooledb, Wt, out);
}

// Round 5
// 219.000 us; speedup vs baseline: 6.8902x; 1.3820x over previous
//
#include <hip/hip_runtime.h>

// Problem constants (from reference setup_inputs)
constexpr int N = 50000;   // nodes
constexpr int E = 800000;  // edges
constexpr int F = 128;     // feature dim
constexpr int U = 256;     // output units

typedef __attribute__((ext_vector_type(8))) short short8;
typedef __attribute__((ext_vector_type(4))) float float4v;

__device__ inline unsigned short f32_to_bf16(float x) {
    unsigned int u = __float_as_uint(x);
    unsigned int r = (u + 0x7fffu + ((u >> 16) & 1u)) >> 16;  // RNE
    return (unsigned short)r;
}

// packed[r]: high 24 bits = edge count, low 40 bits = sum(val) in units of 2^-26
constexpr float FIXED_SCALE = 67108864.0f;       // 2^26
constexpr float FIXED_INV   = 1.4901161193847656e-8f;  // 2^-26

__device__ inline float decode_deg(unsigned long long p) {
    return (float)(p & 0xFFFFFFFFFFull) * FIXED_INV;
}

// ---------------------------------------------------------------------------
// 1) one packed atomic per edge: count++ and sum += val; old value gives the
//    edge's rank within its row (removes permute's atomic pass entirely)
// ---------------------------------------------------------------------------
__global__ __launch_bounds__(256) void hist_kernel(const int* __restrict__ erow,
                                                   const float* __restrict__ eval,
                                                   unsigned long long* __restrict__ packed,
                                                   int* __restrict__ rank) {
    int e = blockIdx.x * 256 + threadIdx.x;
    if (e < E) {
        int r = erow[e];
        unsigned long long add =
            (1ull << 40) | (unsigned long long)(eval[e] * FIXED_SCALE);
        unsigned long long old = atomicAdd(&packed[r], add);
        rank[e] = (int)(old >> 40);
    }
}

// ---------------------------------------------------------------------------
// 2a) per-block sums of counts (196 blocks x 256)
// ---------------------------------------------------------------------------
__global__ __launch_bounds__(256) void blksum_kernel(const unsigned long long* __restrict__ packed,
                                                     int* __restrict__ blk_sum) {
    int i = blockIdx.x * 256 + threadIdx.x;
    int v = (i < N) ? (int)(packed[i] >> 40) : 0;
    #pragma unroll
    for (int off = 32; off > 0; off >>= 1) v += __shfl_down(v, off, 64);
    __shared__ int s[4];
    if ((threadIdx.x & 63) == 0) s[threadIdx.x >> 6] = v;
    __syncthreads();
    if (threadIdx.x == 0) blk_sum[blockIdx.x] = s[0] + s[1] + s[2] + s[3];
}

// ---------------------------------------------------------------------------
// 2b) exclusive scan of the 196 block sums (1 block x 256)
// ---------------------------------------------------------------------------
__global__ __launch_bounds__(256) void scansum_kernel(const int* __restrict__ blk_sum,
                                                      int* __restrict__ blk_off,
                                                      int* __restrict__ row_ptr) {
    __shared__ int sh[256];
    int t = threadIdx.x;
    int v = (t < 196) ? blk_sum[t] : 0;
    sh[t] = v;
    __syncthreads();
    for (int off = 1; off < 256; off <<= 1) {
        int u = (t >= off) ? sh[t - off] : 0;
        __syncthreads();
        sh[t] += u;
        __syncthreads();
    }
    blk_off[t] = sh[t] - v;  // exclusive
    if (t == 0) row_ptr[N] = E;
}

// ---------------------------------------------------------------------------
// 2c) per-block scan + global offset -> row_ptr (196 blocks x 256)
// ---------------------------------------------------------------------------
__global__ __launch_bounds__(256) void blkscan_kernel(const unsigned long long* __restrict__ packed,
                                                      const int* __restrict__ blk_off,
                                                      int* __restrict__ row_ptr) {
    __shared__ int sh[256];
    int t = threadIdx.x;
    int i = blockIdx.x * 256 + t;
    int v = (i < N) ? (int)(packed[i] >> 40) : 0;
    sh[t] = v;
    __syncthreads();
    for (int off = 1; off < 256; off <<= 1) {
        int u = (t >= off) ? sh[t - off] : 0;
        __syncthreads();
        sh[t] += u;
        __syncthreads();
    }
    if (i < N) row_ptr[i] = blk_off[blockIdx.x] + sh[t] - v;
}

// ---------------------------------------------------------------------------
// 3) permute edges into CSR order — NO atomics (rank from hist)
// ---------------------------------------------------------------------------
__global__ __launch_bounds__(256) void permute_kernel(const int* __restrict__ erow,
                                                      const int* __restrict__ ecol,
                                                      const float* __restrict__ eval,
                                                      const int* __restrict__ rank,
                                                      const int* __restrict__ row_ptr,
                                                      int2* __restrict__ csr) {
    int e = blockIdx.x * 256 + threadIdx.x;
    if (e < E) {
        int p = row_ptr[erow[e]] + rank[e];
        csr[p] = make_int2(ecol[e], __float_as_int(eval[e]));
    }
}

// ---------------------------------------------------------------------------
// 4) normalized = rsqrt(deg+1) * feat, stored bf16
// ---------------------------------------------------------------------------
__global__ __launch_bounds__(256) void norm_kernel(const float* __restrict__ feat,
                                                   const unsigned long long* __restrict__ packed,
                                                   unsigned short* __restrict__ nrm) {
    int tid = blockIdx.x * 256 + threadIdx.x;  // exactly N*32 threads
    int node = tid >> 5;
    int q    = tid & 31;
    float iv = rsqrtf(decode_deg(packed[node]) + 1.0f);
    float4 f = ((const float4*)feat)[node * 32 + q];
    ushort4 o;
    o.x = f32_to_bf16(iv * f.x);
    o.y = f32_to_bf16(iv * f.y);
    o.z = f32_to_bf16(iv * f.z);
    o.w = f32_to_bf16(iv * f.w);
    ((ushort4*)nrm)[node * 32 + q] = o;
}

// ---------------------------------------------------------------------------
// 5) gather: pooled[n] = inv^2*feat[n] + sum_e val*nrm[col]  -> bf16 output
//    one wave per node; 4-edge unrolled load batch for MLP
// ---------------------------------------------------------------------------
__global__ __launch_bounds__(256) void gather_kernel(const int* __restrict__ row_ptr,
                                                     const int2* __restrict__ csr,
                                                     const unsigned short* __restrict__ nrm,
                                                     const unsigned long long* __restrict__ packed,
                                                     const float* __restrict__ feat,
                                                     unsigned int* __restrict__ pooledb) {
    int gtid = blockIdx.x * 256 + threadIdx.x;
    int n    = gtid >> 6;
    int lane = threadIdx.x & 63;
    if (n >= N) return;

    float iv  = rsqrtf(decode_deg(packed[n]) + 1.0f);
    float iv2 = iv * iv;
    float2 f = ((const float2*)feat)[n * 64 + lane];
    float acc0 = iv2 * f.x;
    float acc1 = iv2 * f.y;

    int e = row_ptr[n], e1 = row_ptr[n + 1];
    for (; e + 3 < e1; e += 4) {
        int2 p0 = csr[e], p1 = csr[e + 1], p2 = csr[e + 2], p3 = csr[e + 3];
        unsigned int u0 = *(const unsigned int*)&nrm[(size_t)p0.x * F + lane * 2];
        unsigned int u1 = *(const unsigned int*)&nrm[(size_t)p1.x * F + lane * 2];
        unsigned int u2 = *(const unsigned int*)&nrm[(size_t)p2.x * F + lane * 2];
        unsigned int u3 = *(const unsigned int*)&nrm[(size_t)p3.x * F + lane * 2];
        float v0 = __int_as_float(p0.y), v1 = __int_as_float(p1.y);
        float v2 = __int_as_float(p2.y), v3 = __int_as_float(p3.y);
        acc0 += v0 * __uint_as_float(u0 << 16);
        acc1 += v0 * __uint_as_float(u0 & 0xffff0000u);
        acc0 += v1 * __uint_as_float(u1 << 16);
        acc1 += v1 * __uint_as_float(u1 & 0xffff0000u);
        acc0 += v2 * __uint_as_float(u2 << 16);
        acc1 += v2 * __uint_as_float(u2 & 0xffff0000u);
        acc0 += v3 * __uint_as_float(u3 << 16);
        acc1 += v3 * __uint_as_float(u3 & 0xffff0000u);
    }
    for (; e < e1; ++e) {
        int2 p0 = csr[e];
        unsigned int u0 = *(const unsigned int*)&nrm[(size_t)p0.x * F + lane * 2];
        float v0 = __int_as_float(p0.y);
        acc0 += v0 * __uint_as_float(u0 << 16);
        acc1 += v0 * __uint_as_float(u0 & 0xffff0000u);
    }
    pooledb[n * 64 + lane] =
        (unsigned int)f32_to_bf16(acc0) | ((unsigned int)f32_to_bf16(acc1) << 16);
}

// ---------------------------------------------------------------------------
// 6) W [128,256] f32 -> Wt [256,128] bf16 (transposed, for B-fragment reads)
// ---------------------------------------------------------------------------
__global__ __launch_bounds__(256) void wt_kernel(const float* __restrict__ W,
                                                 unsigned short* __restrict__ Wt) {
    int idx = blockIdx.x * 256 + threadIdx.x;  // 32768 = 128*256
    int k = idx >> 8;
    int n = idx & 255;
    Wt[n * F + k] = f32_to_bf16(W[idx]);
}

// ---------------------------------------------------------------------------
// 7) out = relu(pooled_bf16 @ W)  via MFMA 16x16x32 bf16. (unchanged)
// ---------------------------------------------------------------------------
__global__ __launch_bounds__(256) void gemm_mfma_kernel(const unsigned short* __restrict__ Ab,
                                                        const unsigned short* __restrict__ Wt,
                                                        float* __restrict__ out) {
    __shared__ unsigned short As[16384];  // 32 KB, [ks(4)][mt(8)][lane(64)][8]
    __shared__ unsigned short Bs[16384];  // 32 KB, [ks(4)][nt(8)][lane(64)][8]
    const int tid = threadIdx.x;
    const int m0 = blockIdx.x * 128;
    const int n0 = blockIdx.y * 128;

    {
        const int r = tid >> 1;
        const int h = tid & 1;
        const int grow = m0 + r;
        const uint4* asrc = (grow < N) ? (const uint4*)(Ab + (size_t)grow * F) : nullptr;
        const uint4* bsrc = (const uint4*)(Wt + (size_t)(n0 + r) * F);
        #pragma unroll
        for (int j = 0; j < 8; ++j) {
            int o = h * 8 + j;
            int ks = o >> 2, quad = o & 3;
            int slot = ((ks * 8 + (r >> 4)) * 64) + (quad << 4) + (r & 15);
            uint4 av = asrc ? asrc[o] : make_uint4(0u, 0u, 0u, 0u);
            ((uint4*)As)[slot] = av;
            ((uint4*)Bs)[slot] = bsrc[o];
        }
    }
    __syncthreads();

    const int wave = tid >> 6;
    const int lane = tid & 63;
    float4v acc[8][2];
    #pragma unroll
    for (int i = 0; i < 8; ++i) {
        acc[i][0] = (float4v){0.f, 0.f, 0.f, 0.f};
        acc[i][1] = (float4v){0.f, 0.f, 0.f, 0.f};
    }

    #pragma unroll
    for (int ks = 0; ks < 4; ++ks) {
        short8 b0 = *(const short8*)&Bs[(((ks * 8 + wave * 2 + 0) * 64) + lane) * 8];
        short8 b1 = *(const short8*)&Bs[(((ks * 8 + wave * 2 + 1) * 64) + lane) * 8];
        #pragma unroll
        for (int mt = 0; mt < 8; ++mt) {
            short8 a = *(const short8*)&As[(((ks * 8 + mt) * 64) + lane) * 8];
            acc[mt][0] = __builtin_amdgcn_mfma_f32_16x16x32_bf16(a, b0, acc[mt][0], 0, 0, 0);
            acc[mt][1] = __builtin_amdgcn_mfma_f32_16x16x32_bf16(a, b1, acc[mt][1], 0, 0, 0);
        }
    }

    const int quad = lane >> 4;
    const int colt = lane & 15;
    #pragma unroll
    for (int mt = 0; mt < 8; ++mt) {
        #pragma unroll
        for (int nt = 0; nt < 2; ++nt) {
            int col = n0 + (wave * 2 + nt) * 16 + colt;
            #pragma unroll
            for (int i = 0; i < 4; ++i) {
                int row = m0 + mt * 16 + quad * 4 + i;
                if (row < N) out[(size_t)row * U + col] = fmaxf(acc[mt][nt][i], 0.f);
            }
        }
    }
}

// ---------------------------------------------------------------------------
extern "C" void kernel_launch(void* const* d_in, const int* in_sizes, int n_in,
                              void* d_out, int out_size, void* d_ws, size_t ws_size,
                              hipStream_t stream) {
    (void)in_sizes; (void)n_in; (void)out_size; (void)ws_size;

    const float* feat = (const float*)d_in[0];  // [N,128]
    const int*   erow = (const int*)d_in[1];    // [E]
    const int*   ecol = (const int*)d_in[2];    // [E]
    const float* eval = (const float*)d_in[3];  // [E]
    const float* W    = (const float*)d_in[4];  // [128,256]
    float* out = (float*)d_out;                 // [N,256]

    // workspace layout (byte offsets, 64B-aligned)
    char* ws = (char*)d_ws;
    unsigned long long* packed  = (unsigned long long*)(ws + 0);  // N u64 (400000 B)
    int*            row_ptr = (int*)  (ws + 400000);              // N+1
    int*            blk_sum = (int*)  (ws + 600064);              // 256
    int*            blk_off = (int*)  (ws + 601088);              // 256
    int*            rank    = (int*)  (ws + 602112);              // E     (3.2 MB)
    int2*           csr     = (int2*) (ws + 3802112);             // E int2 (6.4 MB)
    unsigned short* Wt      = (unsigned short*)(ws + 10202112);   // 256*128 bf16 (64 KB)
    unsigned short* nrm     = (unsigned short*)(ws + 10267648);   // N*F bf16 (12.8 MB)
    unsigned int*   pooledb = (unsigned int*)  (ws + 23067648);   // N*F bf16 (12.8 MB)
    // total ~35.9 MB

    (void)hipMemsetAsync(ws, 0, 400000, stream);  // packed

    hist_kernel<<<(E + 255) / 256, 256, 0, stream>>>(erow, eval, packed, rank);

    const int SBLK = (N + 255) / 256;  // 196
    blksum_kernel <<<SBLK, 256, 0, stream>>>(packed, blk_sum);
    scansum_kernel<<<1,    256, 0, stream>>>(blk_sum, blk_off, row_ptr);
    blkscan_kernel<<<SBLK, 256, 0, stream>>>(packed, blk_off, row_ptr);

    permute_kernel<<<(E + 255) / 256, 256, 0, stream>>>(erow, ecol, eval, rank, row_ptr, csr);
    norm_kernel<<<(N * 32) / 256, 256, 0, stream>>>(feat, packed, nrm);
    wt_kernel<<<(F * U) / 256, 256, 0, stream>>>(W, Wt);
    gather_kernel<<<(N * 64) / 256, 256, 0, stream>>>(row_ptr, csr, nrm, packed, feat, pooledb);

    dim3 ggrid((N + 127) / 128, U / 128);
    gemm_mfma_kernel<<<ggrid, 256, 0, stream>>>((const unsigned short*)pooledb, Wt, out);
}